// Round 2
// baseline (368.889 us; speedup 1.0000x reference)
//
#include <hip/hip_runtime.h>

#define NS 50000
#define NE 800000
#define XD 64
#define HD 64
#define YD 32

// ---------------- int in-degree count ----------------
__global__ void k_degi(const int* __restrict__ dst, int* __restrict__ deg) {
    int e = blockIdx.x * blockDim.x + threadIdx.x;
    if (e < NE) atomicAdd(&deg[dst[e]], 1);
}

// ---------------- single-block scan: rowptr, cursor, dinv ----------------
__global__ __launch_bounds__(1024) void k_scan(const int* __restrict__ deg,
                                               int* __restrict__ rowptr,
                                               int* __restrict__ cursor,
                                               float* __restrict__ dinv) {
    __shared__ int sums[1024];
    int t = threadIdx.x;
    const int CH = (NS + 1023) / 1024;  // 49
    int beg = t * CH, end = min(beg + CH, NS);
    int s = 0;
    for (int i = beg; i < end; ++i) s += deg[i];
    sums[t] = s;
    __syncthreads();
    int val = s;
    for (int off = 1; off < 1024; off <<= 1) {
        int other = (t >= off) ? sums[t - off] : 0;
        __syncthreads();
        val += other;
        sums[t] = val;
        __syncthreads();
    }
    int run = val - s;  // exclusive prefix of this thread's chunk
    for (int i = beg; i < end; ++i) {
        int dg = deg[i];
        rowptr[i] = run;
        cursor[i] = run;
        dinv[i] = rsqrtf((float)dg + 1.0f);  // +1 = self loop
        run += dg;
    }
    if (t == 0) rowptr[NS] = NE;
}

// ---------------- CSR fill (edges bucketed by dst) ----------------
__global__ void k_fill(const int* __restrict__ src, const int* __restrict__ dst,
                       int* __restrict__ cursor, int* __restrict__ csr) {
    int e = blockIdx.x * blockDim.x + threadIdx.x;
    if (e < NE) {
        int pos = atomicAdd(&cursor[dst[e]], 1);
        csr[pos] = src[e];
    }
}

// ---------------- layer-1 transform: G1[s][f] = dinv[s] * sum_xf x[xf][s]*W1[xf][f]
__global__ __launch_bounds__(256) void k_xw1(const float* __restrict__ x,
                                             const float* __restrict__ W1,
                                             const float* __restrict__ dinv,
                                             float* __restrict__ G1) {
    __shared__ float w[XD * HD];
    for (int i = threadIdx.x; i < XD * HD; i += 256) w[i] = W1[i];
    __syncthreads();
    int s = blockIdx.x * 256 + threadIdx.x;
    if (s >= NS) return;
    float4 acc[HD / 4];
#pragma unroll
    for (int i = 0; i < HD / 4; ++i) acc[i] = make_float4(0.f, 0.f, 0.f, 0.f);
    for (int xf = 0; xf < XD; ++xf) {
        float xv = x[(size_t)xf * NS + s];  // coalesced over s
        const float4* wr = (const float4*)&w[xf * HD];
#pragma unroll
        for (int i = 0; i < HD / 4; ++i) {
            float4 wv = wr[i];
            acc[i].x += xv * wv.x; acc[i].y += xv * wv.y;
            acc[i].z += xv * wv.z; acc[i].w += xv * wv.w;
        }
    }
    float dv = dinv[s];
    float4* out = (float4*)&G1[(size_t)s * HD];
#pragma unroll
    for (int i = 0; i < HD / 4; ++i) {
        acc[i].x *= dv; acc[i].y *= dv; acc[i].z *= dv; acc[i].w *= dv;
        out[i] = acc[i];
    }
}

// ---------------- gather layer 1: one 64-lane wave per node ----------------
// h[d][f] = relu(dinv[d]*(sum_{s in N(d)} G1[s][f] + G1[d][f]) + b1[f])
__global__ __launch_bounds__(256) void k_gather1(const int* __restrict__ rowptr,
                                                 const int* __restrict__ csr,
                                                 const float* __restrict__ G1,
                                                 const float* __restrict__ dinv,
                                                 const float* __restrict__ b1,
                                                 float* __restrict__ h) {
    int wid = (blockIdx.x * 256 + threadIdx.x) >> 6;  // node
    int lane = threadIdx.x & 63;                      // feature
    if (wid >= NS) return;
    int beg = rowptr[wid], end = rowptr[wid + 1];
    float acc = 0.f;
    for (int base = beg; base < end; base += 64) {
        int idx = (base + lane < end) ? csr[base + lane] : 0;  // coalesced batch
        int cnt = min(end - base, 64);
        for (int j = 0; j < cnt; ++j) {
            int s = __shfl(idx, j);                  // broadcast neighbor id
            acc += G1[(size_t)s * HD + lane];        // 256B coalesced row read
        }
    }
    float dv = dinv[wid];
    float v = dv * (acc + G1[(size_t)wid * HD + lane]) + b1[lane];
    h[(size_t)wid * HD + lane] = fmaxf(v, 0.f);
}

// ---------------- layer-2 transform: G2[s][o] = dinv[s] * sum_f h[s][f]*W2[f][o]
__global__ __launch_bounds__(256) void k_l2b(const float* __restrict__ h,
                                             const float* __restrict__ W2,
                                             const float* __restrict__ dinv,
                                             float* __restrict__ G2) {
    __shared__ float w[HD * YD];
    for (int i = threadIdx.x; i < HD * YD; i += 256) w[i] = W2[i];
    __syncthreads();
    int s = blockIdx.x * 256 + threadIdx.x;
    if (s >= NS) return;
    float4 acc[YD / 4];
#pragma unroll
    for (int i = 0; i < YD / 4; ++i) acc[i] = make_float4(0.f, 0.f, 0.f, 0.f);
    const float4* hr = (const float4*)&h[(size_t)s * HD];
    for (int f4 = 0; f4 < HD / 4; ++f4) {
        float4 hv = hr[f4];
        float hh[4] = {hv.x, hv.y, hv.z, hv.w};
#pragma unroll
        for (int j = 0; j < 4; ++j) {
            const float4* wr = (const float4*)&w[(f4 * 4 + j) * YD];
#pragma unroll
            for (int i = 0; i < YD / 4; ++i) {
                float4 wv = wr[i];
                acc[i].x += hh[j] * wv.x; acc[i].y += hh[j] * wv.y;
                acc[i].z += hh[j] * wv.z; acc[i].w += hh[j] * wv.w;
            }
        }
    }
    float dv = dinv[s];
    float4* out = (float4*)&G2[(size_t)s * YD];
#pragma unroll
    for (int i = 0; i < YD / 4; ++i) {
        acc[i].x *= dv; acc[i].y *= dv; acc[i].z *= dv; acc[i].w *= dv;
        out[i] = acc[i];
    }
}

// ---------------- gather layer 2: 32-lane half-wave per node ----------------
__global__ __launch_bounds__(256) void k_gather2(const int* __restrict__ rowptr,
                                                 const int* __restrict__ csr,
                                                 const float* __restrict__ G2,
                                                 const float* __restrict__ dinv,
                                                 float* __restrict__ O2) {
    int hw = (blockIdx.x * 256 + threadIdx.x) >> 5;  // node
    int lane = threadIdx.x & 31;                     // feature
    if (hw >= NS) return;
    int beg = rowptr[hw], end = rowptr[hw + 1];
    float acc = 0.f;
    for (int base = beg; base < end; base += 32) {
        int idx = (base + lane < end) ? csr[base + lane] : 0;
        int cnt = min(end - base, 32);
        for (int j = 0; j < cnt; ++j) {
            int s = __shfl(idx, j, 32);
            acc += G2[(size_t)s * YD + lane];        // 128B coalesced row read
        }
    }
    O2[(size_t)hw * YD + lane] = dinv[hw] * (acc + G2[(size_t)hw * YD + lane]);
}

// ---------------- final epilogue + transpose ----------------
__global__ void k_out(const float* __restrict__ O2, const float* __restrict__ b2,
                      float* __restrict__ out) {
    int s = blockIdx.x * blockDim.x + threadIdx.x;
    if (s >= NS) return;
#pragma unroll
    for (int o = 0; o < YD; ++o) {
        out[(size_t)o * NS + s] = O2[(size_t)s * YD + o] + b2[o];  // coalesced over s
    }
}

extern "C" void kernel_launch(void* const* d_in, const int* in_sizes, int n_in,
                              void* d_out, int out_size, void* d_ws, size_t ws_size,
                              hipStream_t stream) {
    const float* x  = (const float*)d_in[0];
    const float* W1 = (const float*)d_in[1];
    const float* b1 = (const float*)d_in[2];
    const float* W2 = (const float*)d_in[3];
    const float* b2 = (const float*)d_in[4];
    const int* ei   = (const int*)d_in[5];
    const int* src = ei;
    const int* dst = ei + NE;

    // ---- workspace layout ----
    // ints: degi[50000] rowptr[50004] cursor[50000] csr[800000]  (950004 ints, 16B-aligned end)
    // floats: dinv[50000] G1[3.2M] h[3.2M]; G2 aliases G1 (dead after gather1), O2 = G1+1.6M
    int* degi   = (int*)d_ws;
    int* rowptr = degi + 50000;
    int* cursor = rowptr + 50004;
    int* csr    = cursor + 50000;
    float* dinv = (float*)(csr + 800000);
    float* G1   = dinv + 50000;
    float* h    = G1 + 3200000;
    float* G2   = G1;            // reuse: G1 dead after k_gather1
    float* O2   = G1 + 1600000;
    float* out  = (float*)d_out;

    hipMemsetAsync(degi, 0, (size_t)50000 * sizeof(int), stream);

    k_degi<<<(NE + 255) / 256, 256, 0, stream>>>(dst, degi);
    k_scan<<<1, 1024, 0, stream>>>(degi, rowptr, cursor, dinv);
    k_fill<<<(NE + 255) / 256, 256, 0, stream>>>(src, dst, cursor, csr);
    k_xw1<<<(NS + 255) / 256, 256, 0, stream>>>(x, W1, dinv, G1);
    k_gather1<<<(NS * 64 + 255) / 256, 256, 0, stream>>>(rowptr, csr, G1, dinv, b1, h);
    k_l2b<<<(NS + 255) / 256, 256, 0, stream>>>(h, W2, dinv, G2);
    k_gather2<<<(NS * 32 + 255) / 256, 256, 0, stream>>>(rowptr, csr, G2, dinv, O2);
    k_out<<<(NS + 255) / 256, 256, 0, stream>>>(O2, b2, out);
}

// Round 3
// 237.056 us; speedup vs baseline: 1.5561x; 1.5561x over previous
//
#include <hip/hip_runtime.h>

#define NS 50000
#define NE 800000
#define XD 64
#define HD 64
#define YD 32

#define SCAN_CHUNK 256
#define SCAN_NBLK ((NS + SCAN_CHUNK - 1) / SCAN_CHUNK)  // 196

// ---------------- int in-degree count ----------------
__global__ void k_degi(const int* __restrict__ dst, int* __restrict__ deg) {
    int e = blockIdx.x * blockDim.x + threadIdx.x;
    if (e < NE) atomicAdd(&deg[dst[e]], 1);
}

// ---------------- scan stage 1: per-block partial sums ----------------
__global__ __launch_bounds__(256) void k_part(const int* __restrict__ deg,
                                              int* __restrict__ partials) {
    __shared__ int red[256];
    int t = threadIdx.x;
    int i = blockIdx.x * SCAN_CHUNK + t;
    red[t] = (i < NS) ? deg[i] : 0;
    __syncthreads();
    for (int off = 128; off > 0; off >>= 1) {
        if (t < off) red[t] += red[t + off];
        __syncthreads();
    }
    if (t == 0) partials[blockIdx.x] = red[0];
}

// ---------------- scan stage 2: scan the partials (1 tiny block) ----------------
__global__ __launch_bounds__(256) void k_scan2(const int* __restrict__ partials,
                                               int* __restrict__ blockoff) {
    __shared__ int sm[256];
    int t = threadIdx.x;
    int v = (t < SCAN_NBLK) ? partials[t] : 0;
    sm[t] = v;
    __syncthreads();
    int val = v;
    for (int off = 1; off < 256; off <<= 1) {
        int other = (t >= off) ? sm[t - off] : 0;
        __syncthreads();
        val += other;
        sm[t] = val;
        __syncthreads();
    }
    if (t < SCAN_NBLK) blockoff[t] = val - v;  // exclusive
}

// ---------------- scan stage 3: intra-block scan + write rowptr/cursor/dinv ----
__global__ __launch_bounds__(256) void k_apply(const int* __restrict__ deg,
                                               const int* __restrict__ blockoff,
                                               int* __restrict__ rowptr,
                                               int* __restrict__ cursor,
                                               float* __restrict__ dinv) {
    __shared__ int sm[256];
    int t = threadIdx.x;
    int i = blockIdx.x * SCAN_CHUNK + t;
    int dg = (i < NS) ? deg[i] : 0;
    sm[t] = dg;
    __syncthreads();
    int val = dg;
    for (int off = 1; off < 256; off <<= 1) {
        int other = (t >= off) ? sm[t - off] : 0;
        __syncthreads();
        val += other;
        sm[t] = val;
        __syncthreads();
    }
    if (i < NS) {
        int ex = blockoff[blockIdx.x] + val - dg;  // global exclusive prefix
        rowptr[i] = ex;
        cursor[i] = ex;
        dinv[i] = rsqrtf((float)dg + 1.0f);  // +1 = self loop
    }
    if (blockIdx.x == 0 && t == 0) rowptr[NS] = NE;
}

// ---------------- CSR fill (edges bucketed by dst) ----------------
__global__ void k_fill(const int* __restrict__ src, const int* __restrict__ dst,
                       int* __restrict__ cursor, int* __restrict__ csr) {
    int e = blockIdx.x * blockDim.x + threadIdx.x;
    if (e < NE) {
        int pos = atomicAdd(&cursor[dst[e]], 1);
        csr[pos] = src[e];
    }
}

// ---------------- layer-1 transform: G1[s][f] = dinv[s] * sum_xf x[xf][s]*W1[xf][f]
__global__ __launch_bounds__(256) void k_xw1(const float* __restrict__ x,
                                             const float* __restrict__ W1,
                                             const float* __restrict__ dinv,
                                             float* __restrict__ G1) {
    __shared__ float w[XD * HD];
    for (int i = threadIdx.x; i < XD * HD; i += 256) w[i] = W1[i];
    __syncthreads();
    int s = blockIdx.x * 256 + threadIdx.x;
    if (s >= NS) return;
    float4 acc[HD / 4];
#pragma unroll
    for (int i = 0; i < HD / 4; ++i) acc[i] = make_float4(0.f, 0.f, 0.f, 0.f);
    for (int xf = 0; xf < XD; ++xf) {
        float xv = x[(size_t)xf * NS + s];  // coalesced over s
        const float4* wr = (const float4*)&w[xf * HD];
#pragma unroll
        for (int i = 0; i < HD / 4; ++i) {
            float4 wv = wr[i];
            acc[i].x += xv * wv.x; acc[i].y += xv * wv.y;
            acc[i].z += xv * wv.z; acc[i].w += xv * wv.w;
        }
    }
    float dv = dinv[s];
    float4* out = (float4*)&G1[(size_t)s * HD];
#pragma unroll
    for (int i = 0; i < HD / 4; ++i) {
        acc[i].x *= dv; acc[i].y *= dv; acc[i].z *= dv; acc[i].w *= dv;
        out[i] = acc[i];
    }
}

// ---------------- gather layer 1: one 64-lane wave per node ----------------
// h[d][f] = relu(dinv[d]*(sum_{s in N(d)} G1[s][f] + G1[d][f]) + b1[f])
__global__ __launch_bounds__(256) void k_gather1(const int* __restrict__ rowptr,
                                                 const int* __restrict__ csr,
                                                 const float* __restrict__ G1,
                                                 const float* __restrict__ dinv,
                                                 const float* __restrict__ b1,
                                                 float* __restrict__ h) {
    int wid = (blockIdx.x * 256 + threadIdx.x) >> 6;  // node
    int lane = threadIdx.x & 63;                      // feature
    if (wid >= NS) return;
    int beg = rowptr[wid], end = rowptr[wid + 1];
    float acc = 0.f;
    for (int base = beg; base < end; base += 64) {
        int idx = (base + lane < end) ? csr[base + lane] : 0;  // coalesced batch
        int cnt = min(end - base, 64);
        for (int j = 0; j < cnt; ++j) {
            int s = __shfl(idx, j);                  // broadcast neighbor id
            acc += G1[(size_t)s * HD + lane];        // 256B coalesced row read
        }
    }
    float dv = dinv[wid];
    float v = dv * (acc + G1[(size_t)wid * HD + lane]) + b1[lane];
    h[(size_t)wid * HD + lane] = fmaxf(v, 0.f);
}

// ---------------- layer-2 transform: G2[s][o] = dinv[s] * sum_f h[s][f]*W2[f][o]
__global__ __launch_bounds__(256) void k_l2b(const float* __restrict__ h,
                                             const float* __restrict__ W2,
                                             const float* __restrict__ dinv,
                                             float* __restrict__ G2) {
    __shared__ float w[HD * YD];
    for (int i = threadIdx.x; i < HD * YD; i += 256) w[i] = W2[i];
    __syncthreads();
    int s = blockIdx.x * 256 + threadIdx.x;
    if (s >= NS) return;
    float4 acc[YD / 4];
#pragma unroll
    for (int i = 0; i < YD / 4; ++i) acc[i] = make_float4(0.f, 0.f, 0.f, 0.f);
    const float4* hr = (const float4*)&h[(size_t)s * HD];
    for (int f4 = 0; f4 < HD / 4; ++f4) {
        float4 hv = hr[f4];
        float hh[4] = {hv.x, hv.y, hv.z, hv.w};
#pragma unroll
        for (int j = 0; j < 4; ++j) {
            const float4* wr = (const float4*)&w[(f4 * 4 + j) * YD];
#pragma unroll
            for (int i = 0; i < YD / 4; ++i) {
                float4 wv = wr[i];
                acc[i].x += hh[j] * wv.x; acc[i].y += hh[j] * wv.y;
                acc[i].z += hh[j] * wv.z; acc[i].w += hh[j] * wv.w;
            }
        }
    }
    float dv = dinv[s];
    float4* out = (float4*)&G2[(size_t)s * YD];
#pragma unroll
    for (int i = 0; i < YD / 4; ++i) {
        acc[i].x *= dv; acc[i].y *= dv; acc[i].z *= dv; acc[i].w *= dv;
        out[i] = acc[i];
    }
}

// ---------------- gather layer 2: 32-lane half-wave per node ----------------
__global__ __launch_bounds__(256) void k_gather2(const int* __restrict__ rowptr,
                                                 const int* __restrict__ csr,
                                                 const float* __restrict__ G2,
                                                 const float* __restrict__ dinv,
                                                 float* __restrict__ O2) {
    int hw = (blockIdx.x * 256 + threadIdx.x) >> 5;  // node
    int lane = threadIdx.x & 31;                     // feature
    if (hw >= NS) return;
    int beg = rowptr[hw], end = rowptr[hw + 1];
    float acc = 0.f;
    for (int base = beg; base < end; base += 32) {
        int idx = (base + lane < end) ? csr[base + lane] : 0;
        int cnt = min(end - base, 32);
        for (int j = 0; j < cnt; ++j) {
            int s = __shfl(idx, j, 32);
            acc += G2[(size_t)s * YD + lane];        // 128B coalesced row read
        }
    }
    O2[(size_t)hw * YD + lane] = dinv[hw] * (acc + G2[(size_t)hw * YD + lane]);
}

// ---------------- final epilogue + transpose ----------------
__global__ void k_out(const float* __restrict__ O2, const float* __restrict__ b2,
                      float* __restrict__ out) {
    int s = blockIdx.x * blockDim.x + threadIdx.x;
    if (s >= NS) return;
#pragma unroll
    for (int o = 0; o < YD; ++o) {
        out[(size_t)o * NS + s] = O2[(size_t)s * YD + o] + b2[o];  // coalesced over s
    }
}

extern "C" void kernel_launch(void* const* d_in, const int* in_sizes, int n_in,
                              void* d_out, int out_size, void* d_ws, size_t ws_size,
                              hipStream_t stream) {
    const float* x  = (const float*)d_in[0];
    const float* W1 = (const float*)d_in[1];
    const float* b1 = (const float*)d_in[2];
    const float* W2 = (const float*)d_in[3];
    const float* b2 = (const float*)d_in[4];
    const int* ei   = (const int*)d_in[5];
    const int* src = ei;
    const int* dst = ei + NE;

    // ---- workspace layout ----
    int* degi     = (int*)d_ws;
    int* rowptr   = degi + 50000;
    int* cursor   = rowptr + 50004;
    int* csr      = cursor + 50000;
    int* partials = csr + 800000;
    int* blockoff = partials + 256;
    float* dinv   = (float*)(blockoff + 252);  // keep 16B alignment
    float* G1     = dinv + 50000;
    float* h      = G1 + 3200000;
    float* G2     = G1;            // reuse: G1 dead after k_gather1
    float* O2     = G1 + 1600000;
    float* out    = (float*)d_out;

    hipMemsetAsync(degi, 0, (size_t)50000 * sizeof(int), stream);

    k_degi<<<(NE + 255) / 256, 256, 0, stream>>>(dst, degi);
    k_part<<<SCAN_NBLK, 256, 0, stream>>>(degi, partials);
    k_scan2<<<1, 256, 0, stream>>>(partials, blockoff);
    k_apply<<<SCAN_NBLK, 256, 0, stream>>>(degi, blockoff, rowptr, cursor, dinv);
    k_fill<<<(NE + 255) / 256, 256, 0, stream>>>(src, dst, cursor, csr);
    k_xw1<<<(NS + 255) / 256, 256, 0, stream>>>(x, W1, dinv, G1);
    k_gather1<<<(NS * 64 + 255) / 256, 256, 0, stream>>>(rowptr, csr, G1, dinv, b1, h);
    k_l2b<<<(NS + 255) / 256, 256, 0, stream>>>(h, W2, dinv, G2);
    k_gather2<<<(NS * 32 + 255) / 256, 256, 0, stream>>>(rowptr, csr, G2, dinv, O2);
    k_out<<<(NS + 255) / 256, 256, 0, stream>>>(O2, b2, out);
}

// Round 4
// 200.436 us; speedup vs baseline: 1.8404x; 1.1827x over previous
//
#include <hip/hip_runtime.h>

#define NS 50000
#define NE 800000
#define XD 64
#define HD 64
#define YD 32

#define SCAN_CHUNK 256
#define SCAN_NBLK ((NS + SCAN_CHUNK - 1) / SCAN_CHUNK)  // 196

// ---- bf16 helpers (round-to-nearest-even pack, cheap unpack) ----
__device__ __forceinline__ unsigned f2b(float f) {
    union { float f; unsigned u; } c; c.f = f;
    return (c.u + 0x7fffu + ((c.u >> 16) & 1u)) >> 16;
}
__device__ __forceinline__ float blo(unsigned u) {
    union { unsigned u; float f; } c; c.u = u << 16; return c.f;
}
__device__ __forceinline__ float bhi(unsigned u) {
    union { unsigned u; float f; } c; c.u = u & 0xffff0000u; return c.f;
}

// ---------------- int in-degree count ----------------
__global__ void k_degi(const int* __restrict__ dst, int* __restrict__ deg) {
    int e = blockIdx.x * blockDim.x + threadIdx.x;
    if (e < NE) atomicAdd(&deg[__builtin_nontemporal_load(dst + e)], 1);
}

// ---------------- scan stage 1: per-block partial sums ----------------
__global__ __launch_bounds__(256) void k_part(const int* __restrict__ deg,
                                              int* __restrict__ partials) {
    __shared__ int red[256];
    int t = threadIdx.x;
    int i = blockIdx.x * SCAN_CHUNK + t;
    red[t] = (i < NS) ? deg[i] : 0;
    __syncthreads();
    for (int off = 128; off > 0; off >>= 1) {
        if (t < off) red[t] += red[t + off];
        __syncthreads();
    }
    if (t == 0) partials[blockIdx.x] = red[0];
}

// ---------------- scan stage 2: scan the partials (1 tiny block) ----------------
__global__ __launch_bounds__(256) void k_scan2(const int* __restrict__ partials,
                                               int* __restrict__ blockoff) {
    __shared__ int sm[256];
    int t = threadIdx.x;
    int v = (t < SCAN_NBLK) ? partials[t] : 0;
    sm[t] = v;
    __syncthreads();
    int val = v;
    for (int off = 1; off < 256; off <<= 1) {
        int other = (t >= off) ? sm[t - off] : 0;
        __syncthreads();
        val += other;
        sm[t] = val;
        __syncthreads();
    }
    if (t < SCAN_NBLK) blockoff[t] = val - v;  // exclusive
}

// ---------------- scan stage 3: intra-block scan + write rowptr/cursor/dinv ----
__global__ __launch_bounds__(256) void k_apply(const int* __restrict__ deg,
                                               const int* __restrict__ blockoff,
                                               int* __restrict__ rowptr,
                                               int* __restrict__ cursor,
                                               float* __restrict__ dinv) {
    __shared__ int sm[256];
    int t = threadIdx.x;
    int i = blockIdx.x * SCAN_CHUNK + t;
    int dg = (i < NS) ? deg[i] : 0;
    sm[t] = dg;
    __syncthreads();
    int val = dg;
    for (int off = 1; off < 256; off <<= 1) {
        int other = (t >= off) ? sm[t - off] : 0;
        __syncthreads();
        val += other;
        sm[t] = val;
        __syncthreads();
    }
    if (i < NS) {
        int ex = blockoff[blockIdx.x] + val - dg;
        rowptr[i] = ex;
        cursor[i] = ex;
        dinv[i] = rsqrtf((float)dg + 1.0f);  // +1 = self loop
    }
    if (blockIdx.x == 0 && t == 0) rowptr[NS] = NE;
}

// ---------------- CSR fill: uint16 ids, nt edge streams ----------------
__global__ void k_fill(const int* __restrict__ src, const int* __restrict__ dst,
                       int* __restrict__ cursor, unsigned short* __restrict__ csr) {
    int e = blockIdx.x * blockDim.x + threadIdx.x;
    if (e < NE) {
        int d = __builtin_nontemporal_load(dst + e);
        int s = __builtin_nontemporal_load(src + e);
        int pos = atomicAdd(&cursor[d], 1);
        csr[pos] = (unsigned short)s;
    }
}

// ---------------- layer-1 transform -> bf16 G1 ----------------
// G1[s][f] = dinv[s] * sum_xf x[xf][s]*W1[xf][f], packed 2xbf16 per uint
__global__ __launch_bounds__(256) void k_xw1(const float* __restrict__ x,
                                             const float* __restrict__ W1,
                                             const float* __restrict__ dinv,
                                             unsigned* __restrict__ G1h) {
    __shared__ float w[XD * HD];
    for (int i = threadIdx.x; i < XD * HD; i += 256) w[i] = W1[i];
    __syncthreads();
    int s = blockIdx.x * 256 + threadIdx.x;
    if (s >= NS) return;
    float4 acc[HD / 4];
#pragma unroll
    for (int i = 0; i < HD / 4; ++i) acc[i] = make_float4(0.f, 0.f, 0.f, 0.f);
    for (int xf = 0; xf < XD; ++xf) {
        float xv = __builtin_nontemporal_load(&x[(size_t)xf * NS + s]);  // coalesced
        const float4* wr = (const float4*)&w[xf * HD];
#pragma unroll
        for (int i = 0; i < HD / 4; ++i) {
            float4 wv = wr[i];
            acc[i].x += xv * wv.x; acc[i].y += xv * wv.y;
            acc[i].z += xv * wv.z; acc[i].w += xv * wv.w;
        }
    }
    float dv = dinv[s];
    unsigned pk[HD / 2];
#pragma unroll
    for (int i = 0; i < HD / 4; ++i) {
        pk[2 * i]     = f2b(dv * acc[i].x) | (f2b(dv * acc[i].y) << 16);
        pk[2 * i + 1] = f2b(dv * acc[i].z) | (f2b(dv * acc[i].w) << 16);
    }
    uint4* o = (uint4*)&G1h[(size_t)s * (HD / 2)];
#pragma unroll
    for (int i = 0; i < HD / 8; ++i) o[i] = ((uint4*)pk)[i];
}

// ---------------- fused gather-1 + ReLU + layer-2 matvec ----------------
// One 64-lane wave per node as 2x32-lane teams (interleaved neighbor slices),
// each lane holds a bf16 feature pair (4B load per lane).
__global__ __launch_bounds__(256) void k_g1l2(const int* __restrict__ rowptr,
                                              const unsigned short* __restrict__ csr,
                                              const unsigned* __restrict__ G1h,
                                              const float* __restrict__ dinv,
                                              const float* __restrict__ b1,
                                              const float* __restrict__ W2,
                                              unsigned* __restrict__ G2h) {
    __shared__ float w2[HD * YD];   // 8 KB
    __shared__ float bsh[HD];
    __shared__ float hsh[4][HD];    // per-wave h row
    for (int i = threadIdx.x; i < HD * YD; i += 256) w2[i] = W2[i];
    if (threadIdx.x < HD) bsh[threadIdx.x] = b1[threadIdx.x];
    __syncthreads();
    int wv = threadIdx.x >> 6, lane = threadIdx.x & 63;
    int node = blockIdx.x * 4 + wv;         // grid covers NS exactly
    int half = lane >> 5, fp = lane & 31;   // team, feature-pair index
    int beg = rowptr[node], end = rowptr[node + 1];
    float ax = 0.f, ay = 0.f;
    for (int base = beg; base < end; base += 64) {
        int cnt = min(end - base, 64);
        int idx = (lane < cnt) ? (int)__builtin_nontemporal_load(csr + base + lane) : 0;
        int it = (cnt + 1) >> 1;
#pragma unroll 4
        for (int j = 0; j < it; ++j) {
            int nsel = 2 * j + half;
            int s = __shfl(idx, min(nsel, cnt - 1));
            unsigned u = G1h[(size_t)s * 32 + fp];   // 4B/lane, 128B/team
            float m = (nsel < cnt) ? 1.f : 0.f;
            ax = fmaf(m, blo(u), ax);
            ay = fmaf(m, bhi(u), ay);
        }
    }
    ax += __shfl_xor(ax, 32);
    ay += __shfl_xor(ay, 32);
    unsigned us = G1h[(size_t)node * 32 + fp];       // self loop
    float dv = dinv[node];
    float h0 = fmaxf(fmaf(dv, ax + blo(us), bsh[2 * fp]), 0.f);
    float h1 = fmaxf(fmaf(dv, ay + bhi(us), bsh[2 * fp + 1]), 0.f);
    if (half == 0) { hsh[wv][2 * fp] = h0; hsh[wv][2 * fp + 1] = h1; }
    __syncthreads();
    // phase 2: G2[node][o] = dv * sum_f h[f]*W2[f][o]; o=fp, f-range split by half
    float p = 0.f;
    const float* hh = hsh[wv];
#pragma unroll
    for (int f = 0; f < 32; ++f)
        p = fmaf(hh[half * 32 + f], w2[(half * 32 + f) * YD + fp], p);
    p += __shfl_xor(p, 32);
    p *= dv;
    float pn = __shfl_xor(p, 1);  // odd partner's value
    if (half == 0 && (fp & 1) == 0)
        G2h[(size_t)node * 16 + (fp >> 1)] = f2b(p) | (f2b(pn) << 16);
}

// ---------------- gather layer 2: 4x16-lane teams per wave ----------------
__global__ __launch_bounds__(256) void k_gather2(const int* __restrict__ rowptr,
                                                 const unsigned short* __restrict__ csr,
                                                 const unsigned* __restrict__ G2h,
                                                 const float* __restrict__ dinv,
                                                 float2* __restrict__ O2) {
    int wv = threadIdx.x >> 6, lane = threadIdx.x & 63;
    int node = blockIdx.x * 4 + wv;
    int q = lane >> 4, fp = lane & 15;
    int beg = rowptr[node], end = rowptr[node + 1];
    float ax = 0.f, ay = 0.f;
    for (int base = beg; base < end; base += 64) {
        int cnt = min(end - base, 64);
        int idx = (lane < cnt) ? (int)__builtin_nontemporal_load(csr + base + lane) : 0;
        int it = (cnt + 3) >> 2;
#pragma unroll 4
        for (int j = 0; j < it; ++j) {
            int nsel = 4 * j + q;
            int s = __shfl(idx, min(nsel, cnt - 1));
            unsigned u = G2h[(size_t)s * 16 + fp];   // 4B/lane, 64B/team
            float m = (nsel < cnt) ? 1.f : 0.f;
            ax = fmaf(m, blo(u), ax);
            ay = fmaf(m, bhi(u), ay);
        }
    }
    ax += __shfl_xor(ax, 16); ay += __shfl_xor(ay, 16);
    ax += __shfl_xor(ax, 32); ay += __shfl_xor(ay, 32);
    unsigned us = G2h[(size_t)node * 16 + fp];
    float dv = dinv[node];
    if (q == 0)
        O2[(size_t)node * 16 + fp] = make_float2(dv * (ax + blo(us)), dv * (ay + bhi(us)));
}

// ---------------- final epilogue + transpose ----------------
__global__ void k_out(const float* __restrict__ O2, const float* __restrict__ b2,
                      float* __restrict__ out) {
    int s = blockIdx.x * blockDim.x + threadIdx.x;
    if (s >= NS) return;
#pragma unroll
    for (int o = 0; o < YD; ++o) {
        out[(size_t)o * NS + s] = O2[(size_t)s * YD + o] + b2[o];  // coalesced over s
    }
}

extern "C" void kernel_launch(void* const* d_in, const int* in_sizes, int n_in,
                              void* d_out, int out_size, void* d_ws, size_t ws_size,
                              hipStream_t stream) {
    const float* x  = (const float*)d_in[0];
    const float* W1 = (const float*)d_in[1];
    const float* b1 = (const float*)d_in[2];
    const float* W2 = (const float*)d_in[3];
    const float* b2 = (const float*)d_in[4];
    const int* ei   = (const int*)d_in[5];
    const int* src = ei;
    const int* dst = ei + NE;

    // ---- workspace layout (4B words) ----
    int* degi     = (int*)d_ws;            // 50000
    int* rowptr   = degi + 50000;          // 50004
    int* cursor   = rowptr + 50004;        // 50000
    int* partials = cursor + 50000;        // 256
    int* blockoff = partials + 256;        // 256
    unsigned short* csr = (unsigned short*)(blockoff + 256);   // 800000 u16
    float* dinv   = (float*)((int*)(blockoff + 256) + 400000); // after csr
    unsigned* G1h = (unsigned*)(dinv + 50000);   // 50000*32 words (bf16 pairs)
    unsigned* G2h = G1h + (size_t)50000 * 32;    // 50000*16 words
    float* O2     = (float*)(G2h + (size_t)50000 * 16);  // 50000*32 floats
    float* out    = (float*)d_out;

    hipMemsetAsync(degi, 0, (size_t)50000 * sizeof(int), stream);

    k_degi<<<(NE + 255) / 256, 256, 0, stream>>>(dst, degi);
    k_part<<<SCAN_NBLK, 256, 0, stream>>>(degi, partials);
    k_scan2<<<1, 256, 0, stream>>>(partials, blockoff);
    k_apply<<<SCAN_NBLK, 256, 0, stream>>>(degi, blockoff, rowptr, cursor, dinv);
    k_fill<<<(NE + 255) / 256, 256, 0, stream>>>(src, dst, cursor, csr);
    k_xw1<<<(NS + 255) / 256, 256, 0, stream>>>(x, W1, dinv, G1h);
    k_g1l2<<<NS / 4, 256, 0, stream>>>(rowptr, csr, G1h, dinv, b1, W2, G2h);
    k_gather2<<<NS / 4, 256, 0, stream>>>(rowptr, csr, G2h, dinv, (float2*)O2);
    k_out<<<(NS + 255) / 256, 256, 0, stream>>>(O2, b2, out);
}